// Round 2
// baseline (1221.651 us; speedup 1.0000x reference)
//
#include <hip/hip_runtime.h>
#include <hip/hip_fp16.h>

// GCN_Embedding R10: src-quarter phasing for L2-resident gathers.
//  Each dst-bucket's CAP region is sub-partitioned by src>>17 into 4 quarters
//  (sub-caps 9088/9088/9088/7744, 5.4-8.8 sigma margins). All 489 accumulate
//  blocks are co-resident and sweep quarters in order, so the x[src] gather
//  working set per phase is ~2MB -> resident in every XCD's 4MB L2
//  (R9 counters: FETCH 551MB vs 136MB ideal = ~50% L2 miss on the 8MB x).
//  Accumulate unroll 2->4 for gather MLP. k_part sorts by 1956 sub-buckets
//  (u16 offsets, 512-wide scan over 2048 entries, 54KB LDS, 3 blocks/CU).

constexpr int N_NODES = 500000;
constexpr int N_EDGES = 16000000;
constexpr int F = 5;
constexpr int NPB = 1024;                        // nodes per bucket (dst >> 10)
constexpr int K_BKT = (N_NODES + NPB - 1) / NPB; // 489
constexpr int CAP = 35008;                       // edges per bucket slot
constexpr int K_SB = K_BKT * 4;                  // 1956 sub-buckets
constexpr int QCAP = 9088;                       // sub-cap q0..q2 (q3 = 7744)
constexpr int PART_BLOCKS = 1024;
constexpr int CHUNK = N_EDGES / PART_BLOCKS;     // 15625
constexpr int SUB = 3125;                        // LDS-staged sub-chunk (5 rounds)

// ---------- init fixed sub-bucket tails ----------
__global__ void k_init(unsigned* __restrict__ gtail) {
    int i = blockIdx.x * blockDim.x + threadIdx.x;
    if (i < K_SB) {
        unsigned b = (unsigned)i >> 2, q = (unsigned)i & 3u;
        gtail[i] = b * CAP + q * QCAP;
    }
}

// ---------- partition: LDS counting-sort into (dst-bucket, src-quarter) ----------
__global__ __launch_bounds__(512) void k_part(const int* __restrict__ src,
                                              const int* __restrict__ dst,
                                              const float* __restrict__ ew,
                                              unsigned* __restrict__ gtail,
                                              uint2* __restrict__ sorted) {
    __shared__ uint2 stage[SUB];              // 25000 B staged payload
    __shared__ unsigned short sbkt[SUB];      // 6250 B sub-bucket id per slot
    __shared__ unsigned hcnt[2048];           // 8 KB hist (step1) / rank ctr (step4)
    __shared__ unsigned short sexcl[2048];    // 4 KB exclusive offsets (<=3125)
    __shared__ unsigned gb2[2048];            // 8 KB global_base - local_off
    __shared__ unsigned scan512[512];         // 2 KB scan partials
    const int t = threadIdx.x;
    const int base_e = blockIdx.x * CHUNK;

#pragma unroll 1
    for (int rnd = 0; rnd < CHUNK / SUB; ++rnd) {
        const int sub_lo = base_e + rnd * SUB;
        hcnt[t] = 0; hcnt[t + 512] = 0; hcnt[t + 1024] = 0; hcnt[t + 1536] = 0;
        __syncthreads();
        // 1) histogram over 1956 sub-buckets
        for (int e = sub_lo + t; e < sub_lo + SUB; e += 512) {
            unsigned d = (unsigned)dst[e];
            unsigned s = (unsigned)src[e];
            atomicAdd(&hcnt[((d >> 10) << 2) | (s >> 17)], 1u);
        }
        __syncthreads();
        // 2) scan: 4-seq per thread + Hillis-Steele over 512 partials
        unsigned c0 = hcnt[4 * t], c1 = hcnt[4 * t + 1];
        unsigned c2 = hcnt[4 * t + 2], c3 = hcnt[4 * t + 3];
        unsigned ts = c0 + c1 + c2 + c3;
        scan512[t] = ts;
        __syncthreads();
        for (int d = 1; d < 512; d <<= 1) {
            unsigned add = (t >= d) ? scan512[t - d] : 0u;
            __syncthreads();
            scan512[t] += add;
            __syncthreads();
        }
        unsigned eb = scan512[t] - ts;
        sexcl[4 * t]     = (unsigned short)eb;
        sexcl[4 * t + 1] = (unsigned short)(eb + c0);
        sexcl[4 * t + 2] = (unsigned short)(eb + c0 + c1);
        sexcl[4 * t + 3] = (unsigned short)(eb + c0 + c1 + c2);
        __syncthreads();
        // 3) global reservation folded with local offset
        for (int sb = t; sb < K_SB; sb += 512) {
            unsigned cnt = hcnt[sb];
            if (cnt) gb2[sb] = atomicAdd(&gtail[sb], cnt) - (unsigned)sexcl[sb];
        }
        __syncthreads();
        hcnt[t] = 0; hcnt[t + 512] = 0; hcnt[t + 1024] = 0; hcnt[t + 1536] = 0;
        __syncthreads();
        // 4) rank-scatter payload into LDS
        for (int e = sub_lo + t; e < sub_lo + SUB; e += 512) {
            unsigned d = (unsigned)dst[e];
            unsigned s = (unsigned)__builtin_nontemporal_load(src + e);
            unsigned sb = ((d >> 10) << 2) | (s >> 17);
            unsigned p = (unsigned)sexcl[sb] + atomicAdd(&hcnt[sb], 1u);
            uint2 pay;
            pay.x = s | ((d & (NPB - 1u)) << 19);
            pay.y = __float_as_uint(__builtin_nontemporal_load(ew + e));
            stage[p] = pay;
            sbkt[p] = (unsigned short)sb;
        }
        __syncthreads();
        // 5) sub-bucket-ordered writeout
        for (int p = t; p < SUB; p += 512)
            sorted[gb2[sbkt[p]] + p] = stage[p];
        __syncthreads();
    }
}

// ---------- x = h @ W^T, 5 x f16 packed per node in one uint4 ----------
__device__ __forceinline__ uint4 pack5(const float o[F]) {
    __half2 p01 = __floats2half2_rn(o[0], o[1]);
    __half2 p23 = __floats2half2_rn(o[2], o[3]);
    __half2 p4z = __floats2half2_rn(o[4], 0.f);
    uint4 pk;
    pk.x = *(const unsigned*)&p01;
    pk.y = *(const unsigned*)&p23;
    pk.z = *(const unsigned*)&p4z;
    pk.w = 0u;
    return pk;
}

__global__ void k_lin(const float* __restrict__ h, const float* __restrict__ W,
                      uint4* __restrict__ x) {
    int i = blockIdx.x * blockDim.x + threadIdx.x;
    if (i >= N_NODES) return;
    float hv[F], o[F];
#pragma unroll
    for (int k = 0; k < F; ++k) hv[k] = h[i * F + k];
#pragma unroll
    for (int f = 0; f < F; ++f) {
        float acc = 0.f;
#pragma unroll
        for (int k = 0; k < F; ++k) acc = fmaf(hv[k], W[f * F + k], acc);
        o[f] = acc;
    }
    x[i] = pack5(o);
}

// ---------- per-edge accumulate: 3 x ds_pk_add_f16 ----------
__device__ __forceinline__ void edge_accum(unsigned long long pe,
                                           const uint4* __restrict__ x,
                                           __half2* __restrict__ acc) {
    unsigned px = (unsigned)pe;
    float w = __uint_as_float((unsigned)(pe >> 32));
    unsigned srci = px & 0x7FFFFu;
    unsigned dl = px >> 19;
    uint4 v = x[srci];
    float2 f01 = __half22float2(*reinterpret_cast<const __half2*>(&v.x));
    float2 f23 = __half22float2(*reinterpret_cast<const __half2*>(&v.y));
    float2 f4z = __half22float2(*reinterpret_cast<const __half2*>(&v.z));
    __half2* a = acc + dl * 3;
    unsafeAtomicAdd(a + 0, __floats2half2_rn(f01.x * w, f01.y * w));
    unsafeAtomicAdd(a + 1, __floats2half2_rn(f23.x * w, f23.y * w));
    unsafeAtomicAdd(a + 2, __floats2half2_rn(f4z.x * w, 1.0f));   // (f4, degree)
}

// one src-quarter range, unroll-4 for gather MLP (1024 threads)
__device__ __forceinline__ void accum_range(unsigned lo, unsigned hi,
                                            const unsigned long long* __restrict__ sorted,
                                            const uint4* __restrict__ x,
                                            __half2* __restrict__ acc) {
    unsigned e = lo + threadIdx.x;
    for (; e + 3072 < hi; e += 4096) {
        unsigned long long p0 = __builtin_nontemporal_load(sorted + e);
        unsigned long long p1 = __builtin_nontemporal_load(sorted + e + 1024);
        unsigned long long p2 = __builtin_nontemporal_load(sorted + e + 2048);
        unsigned long long p3 = __builtin_nontemporal_load(sorted + e + 3072);
        edge_accum(p0, x, acc);
        edge_accum(p1, x, acc);
        edge_accum(p2, x, acc);
        edge_accum(p3, x, acc);
    }
    for (; e < hi; e += 1024)
        edge_accum(__builtin_nontemporal_load(sorted + e), x, acc);
}

// ---------- per-bucket LDS accumulate + finish + next lin (1024 thr) ----------
__global__ __launch_bounds__(1024) void k_gacc(const unsigned long long* __restrict__ sorted,
                                               const unsigned* __restrict__ gtail,
                                               const uint4* __restrict__ x,
                                               const float* __restrict__ bias,
                                               const float* __restrict__ Wn,
                                               uint4* __restrict__ xn) {
    __shared__ __half2 acc[NPB * 3];
    for (int t = threadIdx.x; t < NPB * 3; t += 1024)
        acc[t] = __floats2half2_rn(0.f, 0.f);
    __syncthreads();
    const unsigned bb = blockIdx.x;
    const uint4 ht = reinterpret_cast<const uint4*>(gtail)[bb];
    const unsigned base = bb * CAP;
    accum_range(base,            ht.x, sorted, x, acc);
    accum_range(base + QCAP,     ht.y, sorted, x, acc);
    accum_range(base + 2 * QCAP, ht.z, sorted, x, acc);
    accum_range(base + 3 * QCAP, ht.w, sorted, x, acc);
    __syncthreads();
    int li = threadIdx.x;
    int node = bb * NPB + li;
    if (node < N_NODES) {
        const __half2* a = acc + li * 3;
        float2 s01 = __half22float2(a[0]);
        float2 s23 = __half22float2(a[1]);
        float2 s4c = __half22float2(a[2]);
        float inv = 1.0f / fmaxf(s4c.y, 1.0f);
        float sv[F] = {s01.x, s01.y, s23.x, s23.y, s4c.x};
        float hv[F], o[F];
#pragma unroll
        for (int f = 0; f < F; ++f) hv[f] = fmaxf(fmaf(sv[f], inv, bias[f]), 0.f);
#pragma unroll
        for (int f = 0; f < F; ++f) {
            float s = 0.f;
#pragma unroll
            for (int kk = 0; kk < F; ++kk) s = fmaf(hv[kk], Wn[f * F + kk], s);
            o[f] = s;
        }
        xn[node] = pack5(o);
    }
}

// ---------- last layer: accumulate + finish + full FC chain (f32 out) ----------
__global__ __launch_bounds__(1024) void k_gfinal(const unsigned long long* __restrict__ sorted,
                                                 const unsigned* __restrict__ gtail,
                                                 const uint4* __restrict__ x,
                                                 const float* __restrict__ b3,
                                                 const float* __restrict__ fcW1, const float* __restrict__ fcb1,
                                                 const float* __restrict__ fcW2, const float* __restrict__ fcb2,
                                                 const float* __restrict__ fcW3, const float* __restrict__ fcb3,
                                                 float* __restrict__ out) {
    __shared__ __half2 acc[NPB * 3];
    for (int t = threadIdx.x; t < NPB * 3; t += 1024)
        acc[t] = __floats2half2_rn(0.f, 0.f);
    __syncthreads();
    const unsigned bb = blockIdx.x;
    const uint4 ht = reinterpret_cast<const uint4*>(gtail)[bb];
    const unsigned base = bb * CAP;
    accum_range(base,            ht.x, sorted, x, acc);
    accum_range(base + QCAP,     ht.y, sorted, x, acc);
    accum_range(base + 2 * QCAP, ht.z, sorted, x, acc);
    accum_range(base + 3 * QCAP, ht.w, sorted, x, acc);
    __syncthreads();
    int li = threadIdx.x;
    int node = bb * NPB + li;
    if (node < N_NODES) {
        const __half2* a = acc + li * 3;
        float2 s01 = __half22float2(a[0]);
        float2 s23 = __half22float2(a[1]);
        float2 s4c = __half22float2(a[2]);
        float inv = 1.0f / fmaxf(s4c.y, 1.0f);
        float sv[F] = {s01.x, s01.y, s23.x, s23.y, s4c.x};
        float h3[F], t1[F], t2[F];
#pragma unroll
        for (int f = 0; f < F; ++f) h3[f] = fmaxf(fmaf(sv[f], inv, b3[f]), 0.f);
#pragma unroll
        for (int f = 0; f < F; ++f) {
            float s = fcb1[f];
#pragma unroll
            for (int kk = 0; kk < F; ++kk) s = fmaf(h3[kk], fcW1[f * F + kk], s);
            t1[f] = fmaxf(s, 0.f);
        }
#pragma unroll
        for (int f = 0; f < F; ++f) {
            float s = fcb2[f];
#pragma unroll
            for (int kk = 0; kk < F; ++kk) s = fmaf(t1[kk], fcW2[f * F + kk], s);
            t2[f] = fmaxf(s, 0.f);
        }
#pragma unroll
        for (int f = 0; f < F; ++f) {
            float s = fcb3[f];
#pragma unroll
            for (int kk = 0; kk < F; ++kk) s = fmaf(t2[kk], fcW3[f * F + kk], s);
            out[node * F + f] = s;
        }
    }
}

extern "C" void kernel_launch(void* const* d_in, const int* in_sizes, int n_in,
                              void* d_out, int out_size, void* d_ws, size_t ws_size,
                              hipStream_t stream) {
    const float* h    = (const float*)d_in[0];
    const int*   ei   = (const int*)d_in[1];
    const float* ew   = (const float*)d_in[2];
    const float* W1   = (const float*)d_in[3];
    const float* b1   = (const float*)d_in[4];
    const float* W2   = (const float*)d_in[5];
    const float* b2   = (const float*)d_in[6];
    const float* W3   = (const float*)d_in[7];
    const float* b3   = (const float*)d_in[8];
    const float* fcW1 = (const float*)d_in[9];
    const float* fcb1 = (const float*)d_in[10];
    const float* fcW2 = (const float*)d_in[11];
    const float* fcb2 = (const float*)d_in[12];
    const float* fcW3 = (const float*)d_in[13];
    const float* fcb3 = (const float*)d_in[14];
    float* out = (float*)d_out;

    const int* srcp = ei;
    const int* dstp = ei + N_EDGES;

    char* ws = (char*)d_ws;
    const size_t MiB = 1024 * 1024;
    unsigned* gtail   = (unsigned*)(ws + 0);           // 1956*4 = 7824 B
    uint4*    xA      = (uint4*)(ws + 1 * MiB);        // 8 MB
    uint4*    xB      = (uint4*)(ws + 10 * MiB);       // 8 MB
    uint2*    sorted  = (uint2*)(ws + 19 * MiB);       // 489*35008*8 = 131 MiB
    const unsigned long long* sorted64 = (const unsigned long long*)sorted;

    dim3 gn((N_NODES + 255) / 256);

    // --- fixed-capacity sub-bucket partition (once, reused by all 3 layers) ---
    k_init<<<(K_SB + 511) / 512, 512, 0, stream>>>(gtail);
    k_part<<<PART_BLOCKS, 512, 0, stream>>>(srcp, dstp, ew, gtail, sorted);

    // --- layer pipeline ---
    k_lin<<<gn, 256, 0, stream>>>(h, W1, xA);
    k_gacc<<<K_BKT, 1024, 0, stream>>>(sorted64, gtail, xA, b1, W2, xB);
    k_gacc<<<K_BKT, 1024, 0, stream>>>(sorted64, gtail, xB, b2, W3, xA);
    k_gfinal<<<K_BKT, 1024, 0, stream>>>(sorted64, gtail, xA, b3,
                                         fcW1, fcb1, fcW2, fcb2, fcW3, fcb3, out);
}

// Round 3
// 934.086 us; speedup vs baseline: 1.3079x; 1.3079x over previous
//
#include <hip/hip_runtime.h>
#include <hip/hip_fp16.h>

// GCN_Embedding R11: atomic-free register accumulation via in-kernel ownership.
//  R10 falsified gather-residency theory (quarter phasing = null for accums).
//  Quantitative fit: accum kernels are DS-atomic-throughput bound (~3.2 cyc per
//  lane RMW; 48M lane-atomics/kernel -> 624K cyc/CU = measured 260us).
//  New accum: per 4096-edge chunk, ONE hist atomic per edge (returned old value
//  = rank), shuffle scan, plain-write scatter into LDS staging, then thread t
//  owns node t and accumulates its contiguous segment in f32 registers.
//  DS atomics cut 3x (48M -> 16M per kernel); degree comes free from cnt[t].
//  k_part reverted to R9's 489-bucket LDS counting sort (known good).

constexpr int N_NODES = 500000;
constexpr int N_EDGES = 16000000;
constexpr int F = 5;
constexpr int NPB = 1024;                        // nodes per bucket (dst >> 10)
constexpr int K_BKT = (N_NODES + NPB - 1) / NPB; // 489
constexpr int CAP = 35008;                       // edges per bucket slot
constexpr int PART_BLOCKS = 1024;
constexpr int CHUNK = N_EDGES / PART_BLOCKS;     // 15625
constexpr int SUB = 3125;                        // k_part LDS-staged sub-chunk
constexpr int ACH = 4096;                        // accum chunk (32KB LDS stage)

// ---------- init fixed bucket tails ----------
__global__ void k_init(unsigned* __restrict__ gtail) {
    int b = blockIdx.x * blockDim.x + threadIdx.x;
    if (b < K_BKT) gtail[b] = (unsigned)(b * CAP);
}

// ---------- partition: LDS counting-sort staging (R9 version) ----------
__global__ __launch_bounds__(512) void k_part(const int* __restrict__ src,
                                              const int* __restrict__ dst,
                                              const float* __restrict__ ew,
                                              unsigned* __restrict__ gtail,
                                              uint2* __restrict__ sorted) {
    __shared__ uint2 stage[SUB];           // 25000 B staged payload
    __shared__ unsigned short sbkt[SUB];   // 6250 B bucket id per staged slot
    __shared__ unsigned hcnt[512];         // per-round bucket counts / rank ctrs
    __shared__ unsigned scn[512];          // scan workspace -> exclusive offsets
    __shared__ unsigned gb2[512];          // global_base - local_off per bucket
    const int t = threadIdx.x;
    const int base_e = blockIdx.x * CHUNK;

#pragma unroll 1
    for (int rnd = 0; rnd < CHUNK / SUB; ++rnd) {
        const int sub_lo = base_e + rnd * SUB;
        hcnt[t] = 0;
        __syncthreads();
        for (int e = sub_lo + t; e < sub_lo + SUB; e += 512)
            atomicAdd(&hcnt[(unsigned)dst[e] >> 10], 1u);
        __syncthreads();
        scn[t] = hcnt[t];
        __syncthreads();
        for (int d = 1; d < 512; d <<= 1) {
            unsigned add = (t >= d) ? scn[t - d] : 0u;
            __syncthreads();
            scn[t] += add;
            __syncthreads();
        }
        unsigned cnt = hcnt[t];
        scn[t] -= cnt; // exclusive scan (own-element, no race)
        if (t < K_BKT && cnt)
            gb2[t] = atomicAdd(&gtail[t], cnt) - scn[t];
        __syncthreads();
        hcnt[t] = 0; // reuse as rank counters
        __syncthreads();
        for (int e = sub_lo + t; e < sub_lo + SUB; e += 512) {
            unsigned d = (unsigned)__builtin_nontemporal_load(dst + e);
            unsigned bkt = d >> 10;
            unsigned p = scn[bkt] + atomicAdd(&hcnt[bkt], 1u);
            uint2 pay;
            pay.x = (unsigned)__builtin_nontemporal_load(src + e) | ((d & (NPB - 1u)) << 19);
            pay.y = __float_as_uint(__builtin_nontemporal_load(ew + e));
            stage[p] = pay;
            sbkt[p] = (unsigned short)bkt;
        }
        __syncthreads();
        for (int p = t; p < SUB; p += 512)
            sorted[gb2[sbkt[p]] + p] = stage[p];
        __syncthreads();
    }
}

// ---------- x = h @ W^T, 5 x f16 packed per node in one uint4 ----------
__device__ __forceinline__ uint4 pack5(const float o[F]) {
    __half2 p01 = __floats2half2_rn(o[0], o[1]);
    __half2 p23 = __floats2half2_rn(o[2], o[3]);
    __half2 p4z = __floats2half2_rn(o[4], 0.f);
    uint4 pk;
    pk.x = *(const unsigned*)&p01;
    pk.y = *(const unsigned*)&p23;
    pk.z = *(const unsigned*)&p4z;
    pk.w = 0u;
    return pk;
}

__global__ void k_lin(const float* __restrict__ h, const float* __restrict__ W,
                      uint4* __restrict__ x) {
    int i = blockIdx.x * blockDim.x + threadIdx.x;
    if (i >= N_NODES) return;
    float hv[F], o[F];
#pragma unroll
    for (int k = 0; k < F; ++k) hv[k] = h[i * F + k];
#pragma unroll
    for (int f = 0; f < F; ++f) {
        float acc = 0.f;
#pragma unroll
        for (int k = 0; k < F; ++k) acc = fmaf(hv[k], W[f * F + k], acc);
        o[f] = acc;
    }
    x[i] = pack5(o);
}

// ---------- chunked ownership accumulate: sums node (bucket*NPB + tid) ----------
// Per chunk: 1 LDS atomic/edge (hist, old value = rank), shuffle scan (2 bars),
// plain-write scatter to LDS staging, owner-thread f32 register accumulation.
__device__ __forceinline__ void accum_bucket(const unsigned long long* __restrict__ sorted,
                                             unsigned lo, unsigned hi,
                                             const uint4* __restrict__ x,
                                             unsigned long long* __restrict__ stage,
                                             unsigned* __restrict__ cnt,
                                             unsigned* __restrict__ excl,
                                             unsigned* __restrict__ wsum,
                                             float acc[F], float& deg) {
    const int t = threadIdx.x;
    const int wid = t >> 6, lane = t & 63;
    for (unsigned cb = lo; cb < hi; cb += ACH) {
        const unsigned n = min((unsigned)ACH, hi - cb);
        cnt[t] = 0;
        __syncthreads();
        // pass1: coalesced load + single hist atomic (returns rank)
        unsigned long long pe[4];
        unsigned dl[4], rk[4];
#pragma unroll
        for (int i = 0; i < 4; ++i) {
            unsigned idx = (unsigned)t + i * 1024u;
            if (idx < n) {
                pe[i] = __builtin_nontemporal_load(sorted + cb + idx);
                dl[i] = ((unsigned)pe[i]) >> 19;
                rk[i] = atomicAdd(&cnt[dl[i]], 1u);
            }
        }
        __syncthreads();
        // scan: wave shfl inclusive scan + wave-partial prefix
        unsigned c = cnt[t];
        unsigned inc = c;
#pragma unroll
        for (int d = 1; d < 64; d <<= 1) {
            unsigned up = __shfl_up(inc, d);
            if (lane >= d) inc += up;
        }
        if (lane == 63) wsum[wid] = inc;
        __syncthreads();
        unsigned wbase = 0;
#pragma unroll
        for (int wv = 0; wv < 15; ++wv)
            if (wv < wid) wbase += wsum[wv];
        unsigned my_excl = wbase + inc - c;
        excl[t] = my_excl;
        __syncthreads();
        // pass2: scatter payloads into dl-sorted LDS staging (plain writes)
#pragma unroll
        for (int i = 0; i < 4; ++i) {
            unsigned idx = (unsigned)t + i * 1024u;
            if (idx < n) stage[excl[dl[i]] + rk[i]] = pe[i];
        }
        __syncthreads();
        // pass3: owner accumulates its contiguous segment in f32 registers
        deg += (float)c;
        for (unsigned i = 0; i < c; ++i) {
            unsigned long long e = stage[my_excl + i];
            unsigned px = (unsigned)e;
            float w = __uint_as_float((unsigned)(e >> 32));
            uint4 v = x[px & 0x7FFFFu];
            float2 f01 = __half22float2(*reinterpret_cast<const __half2*>(&v.x));
            float2 f23 = __half22float2(*reinterpret_cast<const __half2*>(&v.y));
            float2 f4z = __half22float2(*reinterpret_cast<const __half2*>(&v.z));
            acc[0] = fmaf(f01.x, w, acc[0]);
            acc[1] = fmaf(f01.y, w, acc[1]);
            acc[2] = fmaf(f23.x, w, acc[2]);
            acc[3] = fmaf(f23.y, w, acc[3]);
            acc[4] = fmaf(f4z.x, w, acc[4]);
        }
        __syncthreads(); // protect stage/cnt reuse next chunk
    }
}

// ---------- per-bucket accumulate + finish + next lin (1024 thr) ----------
__global__ __launch_bounds__(1024) void k_gacc(const unsigned long long* __restrict__ sorted,
                                               const unsigned* __restrict__ gtail,
                                               const uint4* __restrict__ x,
                                               const float* __restrict__ bias,
                                               const float* __restrict__ Wn,
                                               uint4* __restrict__ xn) {
    __shared__ unsigned long long stage[ACH]; // 32 KB
    __shared__ unsigned cnt[NPB];             // 4 KB
    __shared__ unsigned excl[NPB];            // 4 KB
    __shared__ unsigned wsum[16];
    float acc[F] = {0.f, 0.f, 0.f, 0.f, 0.f};
    float deg = 0.f;
    const unsigned b = blockIdx.x;
    accum_bucket(sorted, b * CAP, gtail[b], x, stage, cnt, excl, wsum, acc, deg);
    int node = b * NPB + threadIdx.x;
    if (node < N_NODES) {
        float inv = 1.0f / fmaxf(deg, 1.0f);
        float hv[F], o[F];
#pragma unroll
        for (int f = 0; f < F; ++f) hv[f] = fmaxf(fmaf(acc[f], inv, bias[f]), 0.f);
#pragma unroll
        for (int f = 0; f < F; ++f) {
            float s = 0.f;
#pragma unroll
            for (int kk = 0; kk < F; ++kk) s = fmaf(hv[kk], Wn[f * F + kk], s);
            o[f] = s;
        }
        xn[node] = pack5(o);
    }
}

// ---------- last layer: accumulate + finish + full FC chain (f32 out) ----------
__global__ __launch_bounds__(1024) void k_gfinal(const unsigned long long* __restrict__ sorted,
                                                 const unsigned* __restrict__ gtail,
                                                 const uint4* __restrict__ x,
                                                 const float* __restrict__ b3,
                                                 const float* __restrict__ fcW1, const float* __restrict__ fcb1,
                                                 const float* __restrict__ fcW2, const float* __restrict__ fcb2,
                                                 const float* __restrict__ fcW3, const float* __restrict__ fcb3,
                                                 float* __restrict__ out) {
    __shared__ unsigned long long stage[ACH];
    __shared__ unsigned cnt[NPB];
    __shared__ unsigned excl[NPB];
    __shared__ unsigned wsum[16];
    float acc[F] = {0.f, 0.f, 0.f, 0.f, 0.f};
    float deg = 0.f;
    const unsigned b = blockIdx.x;
    accum_bucket(sorted, b * CAP, gtail[b], x, stage, cnt, excl, wsum, acc, deg);
    int node = b * NPB + threadIdx.x;
    if (node < N_NODES) {
        float inv = 1.0f / fmaxf(deg, 1.0f);
        float h3[F], t1[F], t2[F];
#pragma unroll
        for (int f = 0; f < F; ++f) h3[f] = fmaxf(fmaf(acc[f], inv, b3[f]), 0.f);
#pragma unroll
        for (int f = 0; f < F; ++f) {
            float s = fcb1[f];
#pragma unroll
            for (int kk = 0; kk < F; ++kk) s = fmaf(h3[kk], fcW1[f * F + kk], s);
            t1[f] = fmaxf(s, 0.f);
        }
#pragma unroll
        for (int f = 0; f < F; ++f) {
            float s = fcb2[f];
#pragma unroll
            for (int kk = 0; kk < F; ++kk) s = fmaf(t1[kk], fcW2[f * F + kk], s);
            t2[f] = fmaxf(s, 0.f);
        }
#pragma unroll
        for (int f = 0; f < F; ++f) {
            float s = fcb3[f];
#pragma unroll
            for (int kk = 0; kk < F; ++kk) s = fmaf(t2[kk], fcW3[f * F + kk], s);
            out[node * F + f] = s;
        }
    }
}

extern "C" void kernel_launch(void* const* d_in, const int* in_sizes, int n_in,
                              void* d_out, int out_size, void* d_ws, size_t ws_size,
                              hipStream_t stream) {
    const float* h    = (const float*)d_in[0];
    const int*   ei   = (const int*)d_in[1];
    const float* ew   = (const float*)d_in[2];
    const float* W1   = (const float*)d_in[3];
    const float* b1   = (const float*)d_in[4];
    const float* W2   = (const float*)d_in[5];
    const float* b2   = (const float*)d_in[6];
    const float* W3   = (const float*)d_in[7];
    const float* b3   = (const float*)d_in[8];
    const float* fcW1 = (const float*)d_in[9];
    const float* fcb1 = (const float*)d_in[10];
    const float* fcW2 = (const float*)d_in[11];
    const float* fcb2 = (const float*)d_in[12];
    const float* fcW3 = (const float*)d_in[13];
    const float* fcb3 = (const float*)d_in[14];
    float* out = (float*)d_out;

    const int* srcp = ei;
    const int* dstp = ei + N_EDGES;

    char* ws = (char*)d_ws;
    const size_t MiB = 1024 * 1024;
    unsigned* gtail   = (unsigned*)(ws + 0);           // 2 KB
    uint4*    xA      = (uint4*)(ws + 1 * MiB);        // 8 MB
    uint4*    xB      = (uint4*)(ws + 10 * MiB);       // 8 MB
    uint2*    sorted  = (uint2*)(ws + 19 * MiB);       // 489*35008*8 = 131 MiB
    const unsigned long long* sorted64 = (const unsigned long long*)sorted;

    dim3 gn((N_NODES + 255) / 256);

    // --- fixed-capacity bucket partition (once, reused by all 3 layers) ---
    k_init<<<1, 512, 0, stream>>>(gtail);
    k_part<<<PART_BLOCKS, 512, 0, stream>>>(srcp, dstp, ew, gtail, sorted);

    // --- layer pipeline ---
    k_lin<<<gn, 256, 0, stream>>>(h, W1, xA);
    k_gacc<<<K_BKT, 1024, 0, stream>>>(sorted64, gtail, xA, b1, W2, xB);
    k_gacc<<<K_BKT, 1024, 0, stream>>>(sorted64, gtail, xB, b2, W3, xA);
    k_gfinal<<<K_BKT, 1024, 0, stream>>>(sorted64, gtail, xA, b3,
                                         fcW1, fcb1, fcW2, fcb2, fcW3, fcb3, out);
}